// Round 5
// baseline (286.430 us; speedup 1.0000x reference)
//
#include <hip/hip_runtime.h>

typedef unsigned short u16;
typedef __attribute__((ext_vector_type(8))) short bf16x8;
typedef __attribute__((ext_vector_type(4))) float f32x4;

#define LOG2E 1.4426950408889634f

__device__ __forceinline__ float bf2f(u16 v) {
    union { unsigned u; float f; } x; x.u = ((unsigned)v) << 16; return x.f;
}
__device__ __forceinline__ u16 f2bf(float f) {
    union { float f; unsigned u; } x; x.f = f;
    unsigned u = x.u;
    u += 0x7FFFu + ((u >> 16) & 1u);   // round-to-nearest-even
    return (u16)(u >> 16);
}

// ---------------------------------------------------------------------------
// K1: time-kernel attention + cross projection. Inputs fp32. (unchanged)
// grid: 256 blocks = 8 b * 32 q-tiles(4), 256 threads (thread = channel d)
// ---------------------------------------------------------------------------
__global__ __launch_bounds__(256)
void k1_attn_cross(const float* __restrict__ x, const float* __restrict__ ts,
                   const float* __restrict__ qy, const float* __restrict__ bww,
                   const float* __restrict__ cw, const float* __restrict__ cb,
                   u16* __restrict__ outb)
{
    const int blk = blockIdx.x;
    const int b  = blk >> 5;
    const int q0 = (blk & 31) * 4;
    const int d  = threadIdx.x;
    const int dm = 128 + (d & 127);

    __shared__ __align__(16) float sc[4][512];
    __shared__ __align__(16) float xs[2][2048];   // 8 rows of 256 f32, dbuf
    __shared__ __align__(16) float attn[4][256];

    for (int i = d; i < 4 * 512; i += 256) {
        int qq = i >> 9, s = i & 511;
        float diff = qy[q0 + qq] - ts[b * 512 + s];
        sc[qq][s] = -diff * diff;
    }
    float w  = bww[d];
    float kk = log1pf(expf(w)) * LOG2E;   // exp(sc*bw) == exp2(sc*kk)

    const float* xb = x + (size_t)b * 512 * 256;
    *(float4*)&xs[0][d * 8]     = *(const float4*)&xb[d * 8];
    *(float4*)&xs[0][d * 8 + 4] = *(const float4*)&xb[d * 8 + 4];
    __syncthreads();

    float num[4] = {0.f, 0.f, 0.f, 0.f}, den[4] = {0.f, 0.f, 0.f, 0.f};
    for (int s0 = 0; s0 < 512; s0 += 8) {
        int cur = (s0 >> 3) & 1;
        if (s0 + 8 < 512) {
            const float* src = &xb[(s0 + 8) * 256 + d * 8];
            *(float4*)&xs[cur ^ 1][d * 8]     = *(const float4*)&src[0];
            *(float4*)&xs[cur ^ 1][d * 8 + 4] = *(const float4*)&src[4];
        }
        #pragma unroll
        for (int ss = 0; ss < 8; ss++) {
            float xv  = xs[cur][ss * 256 + d];
            float mv  = xs[cur][ss * 256 + dm];   // mask in {0,1}
            float mxv = mv * xv;
            #pragma unroll
            for (int qq = 0; qq < 4; qq++) {
                float p = exp2f(sc[qq][s0 + ss] * kk);
                num[qq] += p * mxv;
                den[qq] += p * mv;
            }
        }
        __syncthreads();
    }
    #pragma unroll
    for (int qq = 0; qq < 4; qq++)
        attn[qq][d] = num[qq] / fmaxf(den[qq], 1e-30f);
    __syncthreads();

    float cbv = cb[d];
    float acc[4] = {cbv, cbv, cbv, cbv};
    const float* wr = cw + (size_t)d * 256;
    for (int k0 = 0; k0 < 256; k0 += 4) {
        float4 wv = *(const float4*)&wr[k0];
        float4 a0 = *(const float4*)&attn[0][k0];
        float4 a1 = *(const float4*)&attn[1][k0];
        float4 a2 = *(const float4*)&attn[2][k0];
        float4 a3 = *(const float4*)&attn[3][k0];
        acc[0] += wv.x * a0.x + wv.y * a0.y + wv.z * a0.z + wv.w * a0.w;
        acc[1] += wv.x * a1.x + wv.y * a1.y + wv.z * a1.z + wv.w * a1.w;
        acc[2] += wv.x * a2.x + wv.y * a2.y + wv.z * a2.z + wv.w * a2.w;
        acc[3] += wv.x * a3.x + wv.y * a3.y + wv.z * a3.z + wv.w * a3.w;
    }
    #pragma unroll
    for (int qq = 0; qq < 4; qq++)
        outb[(size_t)(b * 128 + q0 + qq) * 256 + d] = f2bf(acc[qq]);
}

// ---------------------------------------------------------------------------
// K2: xp[z] = outb @ w_ih_z^T + b_ih_z   via MFMA 16x16x32 bf16. (unchanged)
// ---------------------------------------------------------------------------
__global__ __launch_bounds__(256)
void k2_xp(const u16* __restrict__ outb,
           const float* __restrict__ wf, const float* __restrict__ bf_,
           const float* __restrict__ wb, const float* __restrict__ bb_,
           u16* __restrict__ xp)     // [2][1024][384] bf16
{
    const int wid  = threadIdx.x >> 6;
    const int lane = threadIdx.x & 63;
    int gw = blockIdx.x * 4 + wid;           // 0..3071
    int z  = (gw >= 1536) ? 1 : 0;
    int t  = gw - z * 1536;
    int rt = t / 24, nt = t - rt * 24;
    int r0 = rt * 16, n0 = nt * 16;

    const float* W  = z ? wb  : wf;
    const float* Bv = z ? bb_ : bf_;

    const u16*   arow = outb + (size_t)(r0 + (lane & 15)) * 256 + (lane >> 4) * 8;
    const float* brow = W    + (size_t)(n0 + (lane & 15)) * 256 + (lane >> 4) * 8;

    f32x4 acc = {0.f, 0.f, 0.f, 0.f};
    #pragma unroll
    for (int k = 0; k < 8; k++) {
        bf16x8 a = *(const bf16x8*)(arow + k * 32);
        float4 w0 = *(const float4*)(brow + k * 32);
        float4 w1 = *(const float4*)(brow + k * 32 + 4);
        bf16x8 bfrag;
        bfrag[0] = (short)f2bf(w0.x); bfrag[1] = (short)f2bf(w0.y);
        bfrag[2] = (short)f2bf(w0.z); bfrag[3] = (short)f2bf(w0.w);
        bfrag[4] = (short)f2bf(w1.x); bfrag[5] = (short)f2bf(w1.y);
        bfrag[6] = (short)f2bf(w1.z); bfrag[7] = (short)f2bf(w1.w);
        acc = __builtin_amdgcn_mfma_f32_16x16x32_bf16(a, bfrag, acc, 0, 0, 0);
    }
    int col   = n0 + (lane & 15);
    int rbase = r0 + (lane >> 4) * 4;
    float bias = Bv[col];
    u16* xpz = xp + (size_t)z * 1024 * 384;
    #pragma unroll
    for (int i = 0; i < 4; i++)
        xpz[(size_t)(rbase + i) * 384 + col] = f2bf(acc[i] + bias);
}

// ---------------------------------------------------------------------------
// K3: bidirectional GRU, MFMA-batched. 2 blocks (one per direction) x 512 thr.
// Per step: hp[8x384] = h[8x128] @ W_hh^T via 16x16x32 bf16 MFMA, hi/lo split
// (Whi*hhi + Wlo*hhi + Whi*hlo -> ~fp32 accuracy). W frags in VGPRs (loaded
// once). h: fp32 master in gate-owner registers; bf16 hi/lo A-frags in
// XOR-swizzled LDS. xp double-buffered one step ahead. 2 barriers/step.
// ---------------------------------------------------------------------------
__global__ __launch_bounds__(512)
void k3_gru(const u16* __restrict__ xp,       // [2][1024][384] bf16
            const float* __restrict__ whf, const float* __restrict__ bhf,
            const float* __restrict__ whb, const float* __restrict__ bhb,
            u16* __restrict__ hout)           // [2][8][128][128] bf16
{
    const int z    = blockIdx.x;
    const int tid  = threadIdx.x;
    const int wid  = tid >> 6;
    const int lane = tid & 63;

    const float* W  = z ? whb : whf;
    const float* bh = z ? bhb : bhf;

    __shared__ __align__(16) u16   hAhi[16 * 128];  // A-frag hi, swizzled
    __shared__ __align__(16) u16   hAlo[16 * 128];  // A-frag lo, swizzled
    __shared__ __align__(16) float hp[8 * 384];     // MFMA output

    // zero hA (rows 8..15 stay zero forever -> C rows 8..15 are exact zeros)
    for (int i = tid; i < 1024; i += 512) {
        ((unsigned*)hAhi)[i] = 0u;
        ((unsigned*)hAlo)[i] = 0u;
    }

    // ---- W_hh fragments in VGPRs, hi/lo bf16, loaded once ----
    // wave wid owns n-tiles {wid*3 .. wid*3+2}; B-frag: W[n0+(lane&15)][kchunk]
    const int nrow  = wid * 48 + (lane & 15);
    const int kbase = (lane >> 4) * 8;
    bf16x8 Whi[3][4], Wlo[3][4];
    #pragma unroll
    for (int nt = 0; nt < 3; nt++) {
        #pragma unroll
        for (int kt = 0; kt < 4; kt++) {
            const float* src = W + (size_t)(nrow + nt * 16) * 128 + kt * 32 + kbase;
            float4 w0 = *(const float4*)src;
            float4 w1 = *(const float4*)(src + 4);
            float v[8] = {w0.x, w0.y, w0.z, w0.w, w1.x, w1.y, w1.z, w1.w};
            bf16x8 hi, lo;
            #pragma unroll
            for (int j = 0; j < 8; j++) {
                u16 hb16 = f2bf(v[j]);
                hi[j] = (short)hb16;
                lo[j] = (short)f2bf(v[j] - bf2f(hb16));
            }
            Whi[nt][kt] = hi;
            Wlo[nt][kt] = lo;
        }
    }

    // ---- gate-phase constants ----
    const int gd = tid & 127;     // hidden index
    const int gm = tid >> 7;      // batch for unit0; unit1 = gm+4
    const float br = bh[gd], bz = bh[gd + 128], bn = bh[gd + 256];
    float h0 = 0.f, h1 = 0.f;     // fp32 master h for (gm,gd) and (gm+4,gd)

    const u16* xpz = xp + (size_t)z * 1024 * 384 + gd;
    u16* ho = hout + (size_t)z * 8 * 128 * 128 + gd;

    // swizzled LDS index for this thread's h writes: row*128 + ((d>>3)^row)*8 + (d&7)
    const int wi0 = gm * 128       + (((gd >> 3) ^ gm)       << 3) + (gd & 7);
    const int wi1 = (gm + 4) * 128 + (((gd >> 3) ^ (gm + 4)) << 3) + (gd & 7);

    // A-frag read addressing: row = lane&15, chunk = (kt*4 + (lane>>4)) ^ row
    const int arow = lane & 15;
    const int asub = lane >> 4;

    // prologue: xp for first step
    int t0 = z ? 127 : 0;
    u16 c0r = xpz[(size_t)(gm * 128 + t0) * 384];
    u16 c0z = xpz[(size_t)(gm * 128 + t0) * 384 + 128];
    u16 c0n = xpz[(size_t)(gm * 128 + t0) * 384 + 256];
    u16 c1r = xpz[(size_t)((gm + 4) * 128 + t0) * 384];
    u16 c1z = xpz[(size_t)((gm + 4) * 128 + t0) * 384 + 128];
    u16 c1n = xpz[(size_t)((gm + 4) * 128 + t0) * 384 + 256];

    __syncthreads();   // hA zero-init visible

    for (int i = 0; i < 128; i++) {
        int t = z ? (127 - i) : i;

        // prefetch next step's xp (hidden under MFMA phase)
        u16 n0r = 0, n0z = 0, n0n = 0, n1r = 0, n1z = 0, n1n = 0;
        if (i < 127) {
            int tn = z ? (t - 1) : (t + 1);
            n0r = xpz[(size_t)(gm * 128 + tn) * 384];
            n0z = xpz[(size_t)(gm * 128 + tn) * 384 + 128];
            n0n = xpz[(size_t)(gm * 128 + tn) * 384 + 256];
            n1r = xpz[(size_t)((gm + 4) * 128 + tn) * 384];
            n1z = xpz[(size_t)((gm + 4) * 128 + tn) * 384 + 128];
            n1n = xpz[(size_t)((gm + 4) * 128 + tn) * 384 + 256];
        }

        // ---- MFMA phase: hp = h @ W^T (hi/lo split) ----
        bf16x8 Ahi[4], Alo[4];
        #pragma unroll
        for (int kt = 0; kt < 4; kt++) {
            int c = ((kt * 4 + asub) ^ arow) << 3;
            Ahi[kt] = *(const bf16x8*)&hAhi[arow * 128 + c];
            Alo[kt] = *(const bf16x8*)&hAlo[arow * 128 + c];
        }
        f32x4 a0 = {0.f, 0.f, 0.f, 0.f};
        f32x4 a1 = {0.f, 0.f, 0.f, 0.f};
        f32x4 a2 = {0.f, 0.f, 0.f, 0.f};
        #pragma unroll
        for (int kt = 0; kt < 4; kt++) {
            a0 = __builtin_amdgcn_mfma_f32_16x16x32_bf16(Ahi[kt], Whi[0][kt], a0, 0, 0, 0);
            a1 = __builtin_amdgcn_mfma_f32_16x16x32_bf16(Ahi[kt], Whi[1][kt], a1, 0, 0, 0);
            a2 = __builtin_amdgcn_mfma_f32_16x16x32_bf16(Ahi[kt], Whi[2][kt], a2, 0, 0, 0);
            a0 = __builtin_amdgcn_mfma_f32_16x16x32_bf16(Ahi[kt], Wlo[0][kt], a0, 0, 0, 0);
            a1 = __builtin_amdgcn_mfma_f32_16x16x32_bf16(Ahi[kt], Wlo[1][kt], a1, 0, 0, 0);
            a2 = __builtin_amdgcn_mfma_f32_16x16x32_bf16(Ahi[kt], Wlo[2][kt], a2, 0, 0, 0);
            a0 = __builtin_amdgcn_mfma_f32_16x16x32_bf16(Alo[kt], Whi[0][kt], a0, 0, 0, 0);
            a1 = __builtin_amdgcn_mfma_f32_16x16x32_bf16(Alo[kt], Whi[1][kt], a1, 0, 0, 0);
            a2 = __builtin_amdgcn_mfma_f32_16x16x32_bf16(Alo[kt], Whi[2][kt], a2, 0, 0, 0);
        }
        // C layout: col = lane&15 (n within tile), row = (lane>>4)*4 + i (batch)
        if (lane < 32) {
            int m0   = (lane >> 4) * 4;
            int ncol = wid * 48 + (lane & 15);
            #pragma unroll
            for (int q = 0; q < 4; q++) {
                hp[(m0 + q) * 384 + ncol]      = a0[q];
                hp[(m0 + q) * 384 + ncol + 16] = a1[q];
                hp[(m0 + q) * 384 + ncol + 32] = a2[q];
            }
        }
        __syncthreads();

        // ---- gate phase: 2 units per thread ----
        {
            float hr = hp[gm * 384 + gd] + br;
            float hz = hp[gm * 384 + gd + 128] + bz;
            float hn = hp[gm * 384 + gd + 256] + bn;
            float r  = 1.f / (1.f + exp2f(-(bf2f(c0r) + hr) * LOG2E));
            float zz = 1.f / (1.f + exp2f(-(bf2f(c0z) + hz) * LOG2E));
            float nn = bf2f(c0n) + r * hn;
            float e  = exp2f(nn * (2.f * LOG2E));
            float th = 1.f - 2.f / (e + 1.f);
            h0 = (1.f - zz) * th + zz * h0;
            u16 hb16 = f2bf(h0);
            hAhi[wi0] = hb16;
            hAlo[wi0] = f2bf(h0 - bf2f(hb16));
            ho[(size_t)gm * 16384 + t * 128] = hb16;
        }
        {
            float hr = hp[(gm + 4) * 384 + gd] + br;
            float hz = hp[(gm + 4) * 384 + gd + 128] + bz;
            float hn = hp[(gm + 4) * 384 + gd + 256] + bn;
            float r  = 1.f / (1.f + exp2f(-(bf2f(c1r) + hr) * LOG2E));
            float zz = 1.f / (1.f + exp2f(-(bf2f(c1z) + hz) * LOG2E));
            float nn = bf2f(c1n) + r * hn;
            float e  = exp2f(nn * (2.f * LOG2E));
            float th = 1.f - 2.f / (e + 1.f);
            h1 = (1.f - zz) * th + zz * h1;
            u16 hb16 = f2bf(h1);
            hAhi[wi1] = hb16;
            hAlo[wi1] = f2bf(h1 - bf2f(hb16));
            ho[(size_t)(gm + 4) * 16384 + t * 128] = hb16;
        }
        c0r = n0r; c0z = n0z; c0n = n0n;
        c1r = n1r; c1z = n1z; c1n = n1n;
        __syncthreads();
    }
}

// ---------------------------------------------------------------------------
// K4: MLP head. 1024 blocks = (b,t), 128 threads. (unchanged)
// ---------------------------------------------------------------------------
__global__ __launch_bounds__(128)
void k4_mlp(const u16* __restrict__ hout,     // [2][8][128][128] bf16
            const float* __restrict__ w1, const float* __restrict__ b1,
            const float* __restrict__ w2, const float* __restrict__ b2,
            float* __restrict__ out)          // [1024][64] fp32
{
    const int bq  = blockIdx.x;
    const int tid = threadIdx.x;

    __shared__ __align__(16) float hrow[256];
    __shared__ float hid[50];

    const u16* hf = hout + (size_t)bq * 128;
    const u16* hb = hout + (size_t)8 * 128 * 128 + (size_t)bq * 128;
    hrow[tid]       = bf2f(hf[tid]);
    hrow[128 + tid] = bf2f(hb[tid]);
    __syncthreads();

    if (tid < 50) {
        float a = b1[tid];
        const float* wr = w1 + (size_t)tid * 256;
        for (int k0 = 0; k0 < 256; k0 += 8) {
            float4 wv0 = *(const float4*)&wr[k0];
            float4 wv1 = *(const float4*)&wr[k0 + 4];
            float4 h0  = *(const float4*)&hrow[k0];
            float4 h1  = *(const float4*)&hrow[k0 + 4];
            a += wv0.x * h0.x + wv0.y * h0.y + wv0.z * h0.z + wv0.w * h0.w;
            a += wv1.x * h1.x + wv1.y * h1.y + wv1.z * h1.z + wv1.w * h1.w;
        }
        hid[tid] = fmaxf(a, 0.f);
    }
    __syncthreads();
    if (tid < 64) {
        float a = b2[tid];
        const float* wr = w2 + (size_t)tid * 50;
        for (int k = 0; k < 50; k++) a += wr[k] * hid[k];
        out[(size_t)bq * 64 + tid] = a;
    }
}

// ---------------------------------------------------------------------------
// Workspace layout (2.0 MB total):
//   [0,     512K) : outb (bf16, K1 out / K2 in) -- reused as hout by K3/K4
//   [512K,  2.0M) : xp   (bf16, K2 out / K3 in)
// ---------------------------------------------------------------------------
extern "C" void kernel_launch(void* const* d_in, const int* in_sizes, int n_in,
                              void* d_out, int out_size, void* d_ws, size_t ws_size,
                              hipStream_t stream)
{
    const float* x    = (const float*)d_in[0];
    const float* ts   = (const float*)d_in[1];
    const float* qy   = (const float*)d_in[2];
    const float* bww  = (const float*)d_in[3];
    const float* cw   = (const float*)d_in[4];
    const float* cb   = (const float*)d_in[5];
    const float* wihf = (const float*)d_in[6];
    const float* whhf = (const float*)d_in[7];
    const float* bihf = (const float*)d_in[8];
    const float* bhhf = (const float*)d_in[9];
    const float* wihb = (const float*)d_in[10];
    const float* whhb = (const float*)d_in[11];
    const float* bihb = (const float*)d_in[12];
    const float* bhhb = (const float*)d_in[13];
    const float* w1   = (const float*)d_in[14];
    const float* b1   = (const float*)d_in[15];
    const float* w2   = (const float*)d_in[16];
    const float* b2   = (const float*)d_in[17];
    float* out = (float*)d_out;

    char* ws = (char*)d_ws;
    u16* outb = (u16*)ws;                     // 512 KB (1024x256 bf16)
    u16* hout = (u16*)ws;                     // alias: 512 KB (2x8x128x128 bf16)
    u16* xp   = (u16*)(ws + 512 * 1024);      // 1.5 MB (2x1024x384 bf16)

    k1_attn_cross<<<256, 256, 0, stream>>>(x, ts, qy, bww, cw, cb, outb);
    k2_xp<<<768, 256, 0, stream>>>(outb, wihf, bihf, wihb, bihb, xp);
    k3_gru<<<2, 512, 0, stream>>>(xp, whhf, bhhf, whhb, bhhb, hout);
    k4_mlp<<<1024, 128, 0, stream>>>(hout, w1, b1, w2, b2, out);
}

// Round 6
// 219.780 us; speedup vs baseline: 1.3033x; 1.3033x over previous
//
#include <hip/hip_runtime.h>

typedef unsigned short u16;
typedef __attribute__((ext_vector_type(8))) short bf16x8;
typedef __attribute__((ext_vector_type(4))) float f32x4;

#define LOG2E 1.4426950408889634f

__device__ __forceinline__ float bf2f(u16 v) {
    union { unsigned u; float f; } x; x.u = ((unsigned)v) << 16; return x.f;
}
__device__ __forceinline__ u16 f2bf(float f) {
    union { float f; unsigned u; } x; x.f = f;
    unsigned u = x.u;
    u += 0x7FFFu + ((u >> 16) & 1u);   // round-to-nearest-even
    return (u16)(u >> 16);
}
__device__ __forceinline__ float sigm(float x) {
    return __builtin_amdgcn_rcpf(1.f + __builtin_amdgcn_exp2f(-x * LOG2E));
}
__device__ __forceinline__ float tanh_fast(float y) {
    float e = __builtin_amdgcn_exp2f(y * (2.f * LOG2E));
    return 1.f - 2.f * __builtin_amdgcn_rcpf(e + 1.f);   // saturates to +-1 safely
}
// raw barrier: LDS visibility only, NO vmem drain (keeps staging loads in flight)
#define STEP_BAR() asm volatile("s_waitcnt lgkmcnt(0)\ns_barrier" ::: "memory")

// ---------------------------------------------------------------------------
// K1: time-kernel attention + cross projection. Inputs fp32. (unchanged)
// ---------------------------------------------------------------------------
__global__ __launch_bounds__(256)
void k1_attn_cross(const float* __restrict__ x, const float* __restrict__ ts,
                   const float* __restrict__ qy, const float* __restrict__ bww,
                   const float* __restrict__ cw, const float* __restrict__ cb,
                   u16* __restrict__ outb)
{
    const int blk = blockIdx.x;
    const int b  = blk >> 5;
    const int q0 = (blk & 31) * 4;
    const int d  = threadIdx.x;
    const int dm = 128 + (d & 127);

    __shared__ __align__(16) float sc[4][512];
    __shared__ __align__(16) float xs[2][2048];
    __shared__ __align__(16) float attn[4][256];

    for (int i = d; i < 4 * 512; i += 256) {
        int qq = i >> 9, s = i & 511;
        float diff = qy[q0 + qq] - ts[b * 512 + s];
        sc[qq][s] = -diff * diff;
    }
    float w  = bww[d];
    float kk = log1pf(expf(w)) * LOG2E;

    const float* xb = x + (size_t)b * 512 * 256;
    *(float4*)&xs[0][d * 8]     = *(const float4*)&xb[d * 8];
    *(float4*)&xs[0][d * 8 + 4] = *(const float4*)&xb[d * 8 + 4];
    __syncthreads();

    float num[4] = {0.f, 0.f, 0.f, 0.f}, den[4] = {0.f, 0.f, 0.f, 0.f};
    for (int s0 = 0; s0 < 512; s0 += 8) {
        int cur = (s0 >> 3) & 1;
        if (s0 + 8 < 512) {
            const float* src = &xb[(s0 + 8) * 256 + d * 8];
            *(float4*)&xs[cur ^ 1][d * 8]     = *(const float4*)&src[0];
            *(float4*)&xs[cur ^ 1][d * 8 + 4] = *(const float4*)&src[4];
        }
        #pragma unroll
        for (int ss = 0; ss < 8; ss++) {
            float xv  = xs[cur][ss * 256 + d];
            float mv  = xs[cur][ss * 256 + dm];
            float mxv = mv * xv;
            #pragma unroll
            for (int qq = 0; qq < 4; qq++) {
                float p = exp2f(sc[qq][s0 + ss] * kk);
                num[qq] += p * mxv;
                den[qq] += p * mv;
            }
        }
        __syncthreads();
    }
    #pragma unroll
    for (int qq = 0; qq < 4; qq++)
        attn[qq][d] = num[qq] / fmaxf(den[qq], 1e-30f);
    __syncthreads();

    float cbv = cb[d];
    float acc[4] = {cbv, cbv, cbv, cbv};
    const float* wr = cw + (size_t)d * 256;
    for (int k0 = 0; k0 < 256; k0 += 4) {
        float4 wv = *(const float4*)&wr[k0];
        float4 a0 = *(const float4*)&attn[0][k0];
        float4 a1 = *(const float4*)&attn[1][k0];
        float4 a2 = *(const float4*)&attn[2][k0];
        float4 a3 = *(const float4*)&attn[3][k0];
        acc[0] += wv.x * a0.x + wv.y * a0.y + wv.z * a0.z + wv.w * a0.w;
        acc[1] += wv.x * a1.x + wv.y * a1.y + wv.z * a1.z + wv.w * a1.w;
        acc[2] += wv.x * a2.x + wv.y * a2.y + wv.z * a2.z + wv.w * a2.w;
        acc[3] += wv.x * a3.x + wv.y * a3.y + wv.z * a3.z + wv.w * a3.w;
    }
    #pragma unroll
    for (int qq = 0; qq < 4; qq++)
        outb[(size_t)(b * 128 + q0 + qq) * 256 + d] = f2bf(acc[qq]);
}

// ---------------------------------------------------------------------------
// K2: xp via MFMA. NOW writes gate-consumption layout:
//   XP2[z][tau][g][dim][b] bf16, tau = (z ? 127-t : t)  (bwd time-reversed)
// ---------------------------------------------------------------------------
__global__ __launch_bounds__(256)
void k2_xp(const u16* __restrict__ outb,
           const float* __restrict__ wf, const float* __restrict__ bf_,
           const float* __restrict__ wb, const float* __restrict__ bb_,
           u16* __restrict__ xp2)    // [2][128][3][128][8] bf16
{
    const int wid  = threadIdx.x >> 6;
    const int lane = threadIdx.x & 63;
    int gw = blockIdx.x * 4 + wid;
    int z  = (gw >= 1536) ? 1 : 0;
    int t  = gw - z * 1536;
    int rt = t / 24, nt = t - rt * 24;
    int r0 = rt * 16, n0 = nt * 16;

    const float* W  = z ? wb  : wf;
    const float* Bv = z ? bb_ : bf_;

    const u16*   arow = outb + (size_t)(r0 + (lane & 15)) * 256 + (lane >> 4) * 8;
    const float* brow = W    + (size_t)(n0 + (lane & 15)) * 256 + (lane >> 4) * 8;

    f32x4 acc = {0.f, 0.f, 0.f, 0.f};
    #pragma unroll
    for (int k = 0; k < 8; k++) {
        bf16x8 a = *(const bf16x8*)(arow + k * 32);
        float4 w0 = *(const float4*)(brow + k * 32);
        float4 w1 = *(const float4*)(brow + k * 32 + 4);
        bf16x8 bfrag;
        bfrag[0] = (short)f2bf(w0.x); bfrag[1] = (short)f2bf(w0.y);
        bfrag[2] = (short)f2bf(w0.z); bfrag[3] = (short)f2bf(w0.w);
        bfrag[4] = (short)f2bf(w1.x); bfrag[5] = (short)f2bf(w1.y);
        bfrag[6] = (short)f2bf(w1.z); bfrag[7] = (short)f2bf(w1.w);
        acc = __builtin_amdgcn_mfma_f32_16x16x32_bf16(a, bfrag, acc, 0, 0, 0);
    }
    int col   = n0 + (lane & 15);
    int rbase = r0 + (lane >> 4) * 4;
    float bias = Bv[col];
    int g  = col >> 7;
    int dv = col & 127;
    u16* xpz = xp2 + (size_t)z * 393216;
    #pragma unroll
    for (int i = 0; i < 4; i++) {
        int r  = rbase + i;
        int bb = r >> 7;
        int tt = r & 127;
        int tau = z ? (127 - tt) : tt;
        xpz[((size_t)(tau * 3 + g) * 128 + dv) * 8 + bb] = f2bf(acc[i] + bias);
    }
}

// ---------------------------------------------------------------------------
// K3: bidirectional GRU, fully register/LDS-resident recurrence.
// 2 blocks (one per dir) x 512 threads (8 waves).
// Wave w owns output column triple {w*16+0..15, +128, +256} so each thread
// holds r,z,n MFMA results for (m=(l>>4)*4+q, dim=w*16+(l&15)) in registers.
// h: fp32 master in regs; bf16 copy in XOR-swizzled 8-slot LDS history ring
// (doubles as A-frag source and hout staging). W_hh hi/lo bf16 in VGPRs.
// xp staged in 4-step chunks: global->regs one chunk ahead, regs->LDS at
// boundary; per-step raw s_barrier with lgkmcnt-only drain (NO vmcnt).
// ---------------------------------------------------------------------------
#define MFMA_KT(A_, KT) \
    a0 = __builtin_amdgcn_mfma_f32_16x16x32_bf16(A_, Whi[0][KT], a0, 0, 0, 0); \
    a1 = __builtin_amdgcn_mfma_f32_16x16x32_bf16(A_, Whi[1][KT], a1, 0, 0, 0); \
    a2 = __builtin_amdgcn_mfma_f32_16x16x32_bf16(A_, Whi[2][KT], a2, 0, 0, 0); \
    a0 = __builtin_amdgcn_mfma_f32_16x16x32_bf16(A_, Wlo[0][KT], a0, 0, 0, 0); \
    a1 = __builtin_amdgcn_mfma_f32_16x16x32_bf16(A_, Wlo[1][KT], a1, 0, 0, 0); \
    a2 = __builtin_amdgcn_mfma_f32_16x16x32_bf16(A_, Wlo[2][KT], a2, 0, 0, 0);

#define GATE(Q, XR, XZ, XN, HM) { \
    float rr = sigm(bf2f(XR) + a0[Q] + br); \
    float zg = sigm(bf2f(XZ) + a1[Q] + bz); \
    float nn = tanh_fast(bf2f(XN) + rr * (a2[Q] + bn)); \
    HM = (1.f - zg) * nn + zg * HM; \
    u16 hb = f2bf(HM); \
    hist[slotW * 2048 + (m0 + Q) * 128 + (dim ^ ((m0 + Q) << 3))] = hb; }

__global__ __launch_bounds__(512, 2)
void k3_gru(const u16* __restrict__ xp2,      // [2][128][3][128][8] bf16
            const float* __restrict__ whf, const float* __restrict__ bhf,
            const float* __restrict__ whb, const float* __restrict__ bhb,
            u16* __restrict__ hout)           // [2][8][128][128] bf16
{
    const int z   = blockIdx.x;
    const int tid = threadIdx.x;
    const int w   = tid >> 6;
    const int l   = tid & 63;
    const int dim = w * 16 + (l & 15);
    const int m0  = (l >> 4) * 4;

    __shared__ __align__(16) u16 xpbuf[2 * 12288 + 16];  // 48 KB + pad
    __shared__ __align__(16) u16 hist[8 * 2048];         // 32 KB ring (16 rows, top 8 zero)

    const float* W  = z ? whb : whf;
    const float* bh = z ? bhb : bhf;

    // ---- W_hh B-frags in VGPRs, hi/lo bf16, loaded once ----
    const int nr = l & 15;
    const int kb = (l >> 4) * 8;
    bf16x8 Whi[3][4], Wlo[3][4];
    #pragma unroll
    for (int g = 0; g < 3; g++) {
        #pragma unroll
        for (int kt = 0; kt < 4; kt++) {
            const float* src = W + (size_t)(g * 128 + w * 16 + nr) * 128 + kt * 32 + kb;
            float4 w0 = *(const float4*)src;
            float4 w1 = *(const float4*)(src + 4);
            float v[8] = {w0.x, w0.y, w0.z, w0.w, w1.x, w1.y, w1.z, w1.w};
            bf16x8 hi, lo;
            #pragma unroll
            for (int jj = 0; jj < 8; jj++) {
                u16 hb = f2bf(v[jj]);
                hi[jj] = (short)hb;
                lo[jj] = (short)f2bf(v[jj] - bf2f(hb));
            }
            Whi[g][kt] = hi;
            Wlo[g][kt] = lo;
        }
    }

    const float br = bh[dim], bz = bh[dim + 128], bn = bh[dim + 256];
    float hm0 = 0.f, hm1 = 0.f, hm2 = 0.f, hm3 = 0.f;

    const u16* xpz   = xp2  + (size_t)z * 393216;
    u16*       houtz = hout + (size_t)z * 8 * 128 * 128;

    // ---- prologue: stage chunk0 -> LDS buf0, preload chunk1 -> regs ----
    uint4 sr0, sr1, sr2;
    {
        const uint4* g0 = (const uint4*)xpz;
        sr0 = g0[tid]; sr1 = g0[512 + tid]; sr2 = g0[1024 + tid];
        uint4* dbuf = (uint4*)xpbuf;
        dbuf[tid] = sr0; dbuf[512 + tid] = sr1; dbuf[1024 + tid] = sr2;
        const uint4* g1 = (const uint4*)(xpz + 12288);
        sr0 = g1[tid]; sr1 = g1[512 + tid]; sr2 = g1[1024 + tid];
    }
    {   // zero hist (rows 8..15 stay zero forever)
        uint4 zz = {0, 0, 0, 0};
        uint4* hz = (uint4*)hist;
        hz[tid] = zz; hz[512 + tid] = zz; hz[1024 + tid] = zz; hz[1536 + tid] = zz;
    }
    __syncthreads();

    const int m_a = l & 15;
    const int xsw = (m_a & 7) << 3;

    for (int c = 0; c < 32; c++) {
        const int bufb  = (c & 1) * 12288;
        const int sbase = (c & 1) * 4;
        #pragma unroll
        for (int j = 0; j < 4; j++) {
            const int slotW = sbase + j;
            const int slotR = (slotW + 7) & 7;
            // A-frags from history ring (swizzled, conflict-free)
            const u16* hb_ = &hist[slotR * 2048 + m_a * 128];
            bf16x8 A0 = *(const bf16x8*)&hb_[(0 * 32 + kb) ^ xsw];
            bf16x8 A1 = *(const bf16x8*)&hb_[(1 * 32 + kb) ^ xsw];
            bf16x8 A2 = *(const bf16x8*)&hb_[(2 * 32 + kb) ^ xsw];
            bf16x8 A3 = *(const bf16x8*)&hb_[(3 * 32 + kb) ^ xsw];

            f32x4 a0 = {0.f, 0.f, 0.f, 0.f};
            f32x4 a1 = {0.f, 0.f, 0.f, 0.f};
            f32x4 a2 = {0.f, 0.f, 0.f, 0.f};
            MFMA_KT(A0, 0)
            MFMA_KT(A1, 1)
            MFMA_KT(A2, 2)
            MFMA_KT(A3, 3)

            if (l < 32) {   // gate phase: rows m0..m0+3 valid (m0 in {0,4})
                const int xb = bufb + j * 3072 + dim * 8 + m0;
                ushort4 X0 = *(const ushort4*)&xpbuf[xb];
                ushort4 X1 = *(const ushort4*)&xpbuf[xb + 1024];
                ushort4 X2 = *(const ushort4*)&xpbuf[xb + 2048];
                GATE(0, X0.x, X1.x, X2.x, hm0)
                GATE(1, X0.y, X1.y, X2.y, hm1)
                GATE(2, X0.z, X1.z, X2.z, hm2)
                GATE(3, X0.w, X1.w, X2.w, hm3)
            }
            STEP_BAR();
        }
        // ---- chunk boundary ----
        if (c < 31) {   // write prefetched chunk c+1 into the other buffer
            uint4* dbuf = (uint4*)&xpbuf[((c + 1) & 1) * 12288];
            dbuf[tid] = sr0; dbuf[512 + tid] = sr1; dbuf[1024 + tid] = sr2;
        }
        {   // dump this chunk's 4 h-slots to hout (bf16 passthrough)
            const int sl = tid >> 7;
            const int bb = (tid >> 4) & 7;
            const int d0 = (tid & 15) * 8;
            int i = c * 4 + sl;
            int t = z ? (127 - i) : i;
            uint4 hv = *(const uint4*)&hist[(sbase + sl) * 2048 + bb * 128 + (d0 ^ (bb << 3))];
            *(uint4*)&houtz[(size_t)bb * 16384 + t * 128 + d0] = hv;
        }
        if (c < 30) {   // issue loads for chunk c+2 (land during next chunk)
            const uint4* gs = (const uint4*)(xpz + (size_t)(c + 2) * 12288);
            sr0 = gs[tid]; sr1 = gs[512 + tid]; sr2 = gs[1024 + tid];
        }
        STEP_BAR();
    }
}

// ---------------------------------------------------------------------------
// K4: MLP head. 1024 blocks = (b,t), 128 threads. (unchanged)
// ---------------------------------------------------------------------------
__global__ __launch_bounds__(128)
void k4_mlp(const u16* __restrict__ hout,
            const float* __restrict__ w1, const float* __restrict__ b1,
            const float* __restrict__ w2, const float* __restrict__ b2,
            float* __restrict__ out)
{
    const int bq  = blockIdx.x;
    const int tid = threadIdx.x;

    __shared__ __align__(16) float hrow[256];
    __shared__ float hid[50];

    const u16* hf = hout + (size_t)bq * 128;
    const u16* hb = hout + (size_t)8 * 128 * 128 + (size_t)bq * 128;
    hrow[tid]       = bf2f(hf[tid]);
    hrow[128 + tid] = bf2f(hb[tid]);
    __syncthreads();

    if (tid < 50) {
        float a = b1[tid];
        const float* wr = w1 + (size_t)tid * 256;
        for (int k0 = 0; k0 < 256; k0 += 8) {
            float4 wv0 = *(const float4*)&wr[k0];
            float4 wv1 = *(const float4*)&wr[k0 + 4];
            float4 h0  = *(const float4*)&hrow[k0];
            float4 h1  = *(const float4*)&hrow[k0 + 4];
            a += wv0.x * h0.x + wv0.y * h0.y + wv0.z * h0.z + wv0.w * h0.w;
            a += wv1.x * h1.x + wv1.y * h1.y + wv1.z * h1.z + wv1.w * h1.w;
        }
        hid[tid] = fmaxf(a, 0.f);
    }
    __syncthreads();
    if (tid < 64) {
        float a = b2[tid];
        const float* wr = w2 + (size_t)tid * 50;
        for (int k = 0; k < 50; k++) a += wr[k] * hid[k];
        out[(size_t)bq * 64 + tid] = a;
    }
}

// ---------------------------------------------------------------------------
// Workspace (2.0 MB): [0,512K) outb (K1->K2), reused as hout (K3->K4);
//                     [512K,2.0M) XP2 (K2->K3, gate-consumption layout).
// ---------------------------------------------------------------------------
extern "C" void kernel_launch(void* const* d_in, const int* in_sizes, int n_in,
                              void* d_out, int out_size, void* d_ws, size_t ws_size,
                              hipStream_t stream)
{
    const float* x    = (const float*)d_in[0];
    const float* ts   = (const float*)d_in[1];
    const float* qy   = (const float*)d_in[2];
    const float* bww  = (const float*)d_in[3];
    const float* cw   = (const float*)d_in[4];
    const float* cb   = (const float*)d_in[5];
    const float* wihf = (const float*)d_in[6];
    const float* whhf = (const float*)d_in[7];
    const float* bihf = (const float*)d_in[8];
    const float* bhhf = (const float*)d_in[9];
    const float* wihb = (const float*)d_in[10];
    const float* whhb = (const float*)d_in[11];
    const float* bihb = (const float*)d_in[12];
    const float* bhhb = (const float*)d_in[13];
    const float* w1   = (const float*)d_in[14];
    const float* b1   = (const float*)d_in[15];
    const float* w2   = (const float*)d_in[16];
    const float* b2   = (const float*)d_in[17];
    float* out = (float*)d_out;

    char* ws = (char*)d_ws;
    u16* outb = (u16*)ws;                     // 512 KB
    u16* hout = (u16*)ws;                     // alias (outb dead after K2)
    u16* xp2  = (u16*)(ws + 512 * 1024);      // 1.5 MB

    k1_attn_cross<<<256, 256, 0, stream>>>(x, ts, qy, bww, cw, cb, outb);
    k2_xp<<<768, 256, 0, stream>>>(outb, wihf, bihf, wihb, bihb, xp2);
    k3_gru<<<2, 512, 0, stream>>>(xp2, whhf, bhhf, whhb, bhhb, hout);
    k4_mlp<<<1024, 128, 0, stream>>>(hout, w1, b1, w2, b2, out);
}

// Round 8
// 197.175 us; speedup vs baseline: 1.4527x; 1.1146x over previous
//
#include <hip/hip_runtime.h>

typedef unsigned short u16;
typedef __attribute__((ext_vector_type(8))) short bf16x8;
typedef __attribute__((ext_vector_type(4))) float f32x4;

#define LOG2E 1.4426950408889634f

__device__ __forceinline__ float bf2f(u16 v) {
    union { unsigned u; float f; } x; x.u = ((unsigned)v) << 16; return x.f;
}
__device__ __forceinline__ u16 f2bf(float f) {
    union { float f; unsigned u; } x; x.f = f;
    unsigned u = x.u;
    u += 0x7FFFu + ((u >> 16) & 1u);   // round-to-nearest-even
    return (u16)(u >> 16);
}
__device__ __forceinline__ float sigm(float x) {
    return __builtin_amdgcn_rcpf(1.f + __builtin_amdgcn_exp2f(-x * LOG2E));
}
__device__ __forceinline__ float tanh_fast(float y) {
    float e = __builtin_amdgcn_exp2f(y * (2.f * LOG2E));
    return 1.f - 2.f * __builtin_amdgcn_rcpf(e + 1.f);   // saturates to +-1 safely
}
// raw barrier: LDS visibility only, NO vmem drain (keeps prefetch/stores in flight)
#define STEP_BAR() asm volatile("s_waitcnt lgkmcnt(0)\ns_barrier" ::: "memory")

// ---------------------------------------------------------------------------
// K1: time-kernel attention + cross projection. Inputs fp32. (unchanged)
// ---------------------------------------------------------------------------
__global__ __launch_bounds__(256)
void k1_attn_cross(const float* __restrict__ x, const float* __restrict__ ts,
                   const float* __restrict__ qy, const float* __restrict__ bww,
                   const float* __restrict__ cw, const float* __restrict__ cb,
                   u16* __restrict__ outb)
{
    const int blk = blockIdx.x;
    const int b  = blk >> 5;
    const int q0 = (blk & 31) * 4;
    const int d  = threadIdx.x;
    const int dm = 128 + (d & 127);

    __shared__ __align__(16) float sc[4][512];
    __shared__ __align__(16) float xs[2][2048];
    __shared__ __align__(16) float attn[4][256];

    for (int i = d; i < 4 * 512; i += 256) {
        int qq = i >> 9, s = i & 511;
        float diff = qy[q0 + qq] - ts[b * 512 + s];
        sc[qq][s] = -diff * diff;
    }
    float w  = bww[d];
    float kk = log1pf(expf(w)) * LOG2E;

    const float* xb = x + (size_t)b * 512 * 256;
    *(float4*)&xs[0][d * 8]     = *(const float4*)&xb[d * 8];
    *(float4*)&xs[0][d * 8 + 4] = *(const float4*)&xb[d * 8 + 4];
    __syncthreads();

    float num[4] = {0.f, 0.f, 0.f, 0.f}, den[4] = {0.f, 0.f, 0.f, 0.f};
    for (int s0 = 0; s0 < 512; s0 += 8) {
        int cur = (s0 >> 3) & 1;
        if (s0 + 8 < 512) {
            const float* src = &xb[(s0 + 8) * 256 + d * 8];
            *(float4*)&xs[cur ^ 1][d * 8]     = *(const float4*)&src[0];
            *(float4*)&xs[cur ^ 1][d * 8 + 4] = *(const float4*)&src[4];
        }
        #pragma unroll
        for (int ss = 0; ss < 8; ss++) {
            float xv  = xs[cur][ss * 256 + d];
            float mv  = xs[cur][ss * 256 + dm];
            float mxv = mv * xv;
            #pragma unroll
            for (int qq = 0; qq < 4; qq++) {
                float p = exp2f(sc[qq][s0 + ss] * kk);
                num[qq] += p * mxv;
                den[qq] += p * mv;
            }
        }
        __syncthreads();
    }
    #pragma unroll
    for (int qq = 0; qq < 4; qq++)
        attn[qq][d] = num[qq] / fmaxf(den[qq], 1e-30f);
    __syncthreads();

    float cbv = cb[d];
    float acc[4] = {cbv, cbv, cbv, cbv};
    const float* wr = cw + (size_t)d * 256;
    for (int k0 = 0; k0 < 256; k0 += 4) {
        float4 wv = *(const float4*)&wr[k0];
        float4 a0 = *(const float4*)&attn[0][k0];
        float4 a1 = *(const float4*)&attn[1][k0];
        float4 a2 = *(const float4*)&attn[2][k0];
        float4 a3 = *(const float4*)&attn[3][k0];
        acc[0] += wv.x * a0.x + wv.y * a0.y + wv.z * a0.z + wv.w * a0.w;
        acc[1] += wv.x * a1.x + wv.y * a1.y + wv.z * a1.z + wv.w * a1.w;
        acc[2] += wv.x * a2.x + wv.y * a2.y + wv.z * a2.z + wv.w * a2.w;
        acc[3] += wv.x * a3.x + wv.y * a3.y + wv.z * a3.z + wv.w * a3.w;
    }
    #pragma unroll
    for (int qq = 0; qq < 4; qq++)
        outb[(size_t)(b * 128 + q0 + qq) * 256 + d] = f2bf(acc[qq]);
}

// ---------------------------------------------------------------------------
// K2: xp via MFMA, gate-consumption layout XP2[z][tau][g][dim][b] bf16,
// tau = (z ? 127-t : t). (unchanged)
// ---------------------------------------------------------------------------
__global__ __launch_bounds__(256)
void k2_xp(const u16* __restrict__ outb,
           const float* __restrict__ wf, const float* __restrict__ bf_,
           const float* __restrict__ wb, const float* __restrict__ bb_,
           u16* __restrict__ xp2)    // [2][128][3][128][8] bf16
{
    const int wid  = threadIdx.x >> 6;
    const int lane = threadIdx.x & 63;
    int gw = blockIdx.x * 4 + wid;
    int z  = (gw >= 1536) ? 1 : 0;
    int t  = gw - z * 1536;
    int rt = t / 24, nt = t - rt * 24;
    int r0 = rt * 16, n0 = nt * 16;

    const float* W  = z ? wb  : wf;
    const float* Bv = z ? bb_ : bf_;

    const u16*   arow = outb + (size_t)(r0 + (lane & 15)) * 256 + (lane >> 4) * 8;
    const float* brow = W    + (size_t)(n0 + (lane & 15)) * 256 + (lane >> 4) * 8;

    f32x4 acc = {0.f, 0.f, 0.f, 0.f};
    #pragma unroll
    for (int k = 0; k < 8; k++) {
        bf16x8 a = *(const bf16x8*)(arow + k * 32);
        float4 w0 = *(const float4*)(brow + k * 32);
        float4 w1 = *(const float4*)(brow + k * 32 + 4);
        bf16x8 bfrag;
        bfrag[0] = (short)f2bf(w0.x); bfrag[1] = (short)f2bf(w0.y);
        bfrag[2] = (short)f2bf(w0.z); bfrag[3] = (short)f2bf(w0.w);
        bfrag[4] = (short)f2bf(w1.x); bfrag[5] = (short)f2bf(w1.y);
        bfrag[6] = (short)f2bf(w1.z); bfrag[7] = (short)f2bf(w1.w);
        acc = __builtin_amdgcn_mfma_f32_16x16x32_bf16(a, bfrag, acc, 0, 0, 0);
    }
    int col   = n0 + (lane & 15);
    int rbase = r0 + (lane >> 4) * 4;
    float bias = Bv[col];
    int g  = col >> 7;
    int dv = col & 127;
    u16* xpz = xp2 + (size_t)z * 393216;
    #pragma unroll
    for (int i = 0; i < 4; i++) {
        int r  = rbase + i;
        int bb = r >> 7;
        int tt = r & 127;
        int tau = z ? (127 - tt) : tt;
        xpz[((size_t)(tau * 3 + g) * 128 + dv) * 8 + bb] = f2bf(acc[i] + bias);
    }
}

// ---------------------------------------------------------------------------
// K3: bidirectional GRU, 8 blocks = (dir z, batch-pair bp), 512 thr (8 waves).
// M=2 batches per block. Wave w owns col triple {w*16+0..15, +128, +256}.
// h: fp32 master in regs; bf16 copy in 2-slot LDS ring (1 KB). W_hh hi/lo
// bf16 in VGPRs, separate hi/lo accumulators. xp straight from global with
// 2-step-ahead register prefetch. ONE raw barrier per step (lgkmcnt only).
// hout written as direct 2B stores at ACTUAL time tw = z ? 127-T : T
// (xp2 is tau-indexed; hout must be t-indexed -- round-7 bug).
// ---------------------------------------------------------------------------
#define K3_STEP(T, XR, XZ, XN) {                                              \
    const int rslot = ((T) + 1) & 1, wslot = (T) & 1;                         \
    bf16x8 A0 = {0,0,0,0,0,0,0,0}, A1 = {0,0,0,0,0,0,0,0};                    \
    bf16x8 A2 = {0,0,0,0,0,0,0,0}, A3 = {0,0,0,0,0,0,0,0};                    \
    if (nr < 2) {                                                             \
        A0 = *(const bf16x8*)&hist[rslot][nr][kb];                            \
        A1 = *(const bf16x8*)&hist[rslot][nr][32 + kb];                       \
        A2 = *(const bf16x8*)&hist[rslot][nr][64 + kb];                       \
        A3 = *(const bf16x8*)&hist[rslot][nr][96 + kb];                       \
    }                                                                         \
    f32x4 h0_ = {0.f,0.f,0.f,0.f}, h1_ = h0_, h2_ = h0_;                      \
    f32x4 l0_ = h0_, l1_ = h0_, l2_ = h0_;                                    \
    h0_ = __builtin_amdgcn_mfma_f32_16x16x32_bf16(A0, Whi[0][0], h0_, 0,0,0); \
    h1_ = __builtin_amdgcn_mfma_f32_16x16x32_bf16(A0, Whi[1][0], h1_, 0,0,0); \
    h2_ = __builtin_amdgcn_mfma_f32_16x16x32_bf16(A0, Whi[2][0], h2_, 0,0,0); \
    l0_ = __builtin_amdgcn_mfma_f32_16x16x32_bf16(A0, Wlo[0][0], l0_, 0,0,0); \
    l1_ = __builtin_amdgcn_mfma_f32_16x16x32_bf16(A0, Wlo[1][0], l1_, 0,0,0); \
    l2_ = __builtin_amdgcn_mfma_f32_16x16x32_bf16(A0, Wlo[2][0], l2_, 0,0,0); \
    h0_ = __builtin_amdgcn_mfma_f32_16x16x32_bf16(A1, Whi[0][1], h0_, 0,0,0); \
    h1_ = __builtin_amdgcn_mfma_f32_16x16x32_bf16(A1, Whi[1][1], h1_, 0,0,0); \
    h2_ = __builtin_amdgcn_mfma_f32_16x16x32_bf16(A1, Whi[2][1], h2_, 0,0,0); \
    l0_ = __builtin_amdgcn_mfma_f32_16x16x32_bf16(A1, Wlo[0][1], l0_, 0,0,0); \
    l1_ = __builtin_amdgcn_mfma_f32_16x16x32_bf16(A1, Wlo[1][1], l1_, 0,0,0); \
    l2_ = __builtin_amdgcn_mfma_f32_16x16x32_bf16(A1, Wlo[2][1], l2_, 0,0,0); \
    h0_ = __builtin_amdgcn_mfma_f32_16x16x32_bf16(A2, Whi[0][2], h0_, 0,0,0); \
    h1_ = __builtin_amdgcn_mfma_f32_16x16x32_bf16(A2, Whi[1][2], h1_, 0,0,0); \
    h2_ = __builtin_amdgcn_mfma_f32_16x16x32_bf16(A2, Whi[2][2], h2_, 0,0,0); \
    l0_ = __builtin_amdgcn_mfma_f32_16x16x32_bf16(A2, Wlo[0][2], l0_, 0,0,0); \
    l1_ = __builtin_amdgcn_mfma_f32_16x16x32_bf16(A2, Wlo[1][2], l1_, 0,0,0); \
    l2_ = __builtin_amdgcn_mfma_f32_16x16x32_bf16(A2, Wlo[2][2], l2_, 0,0,0); \
    h0_ = __builtin_amdgcn_mfma_f32_16x16x32_bf16(A3, Whi[0][3], h0_, 0,0,0); \
    h1_ = __builtin_amdgcn_mfma_f32_16x16x32_bf16(A3, Whi[1][3], h1_, 0,0,0); \
    h2_ = __builtin_amdgcn_mfma_f32_16x16x32_bf16(A3, Whi[2][3], h2_, 0,0,0); \
    l0_ = __builtin_amdgcn_mfma_f32_16x16x32_bf16(A3, Wlo[0][3], l0_, 0,0,0); \
    l1_ = __builtin_amdgcn_mfma_f32_16x16x32_bf16(A3, Wlo[1][3], l1_, 0,0,0); \
    l2_ = __builtin_amdgcn_mfma_f32_16x16x32_bf16(A3, Wlo[2][3], l2_, 0,0,0); \
    if (l < 16) {                                                             \
        f32x4 a0 = h0_ + l0_, a1 = h1_ + l1_, a2 = h2_ + l2_;                 \
        const int tw = z ? (127 - (T)) : (T);                                 \
        {   /* m = 0 */                                                       \
            float rr = sigm(bf2f((u16)((XR) & 0xffff)) + a0[0] + br);         \
            float zg = sigm(bf2f((u16)((XZ) & 0xffff)) + a1[0] + bz);         \
            float nn = tanh_fast(bf2f((u16)((XN) & 0xffff)) + rr * (a2[0] + bn)); \
            hm0 = (1.f - zg) * nn + zg * hm0;                                 \
            u16 hb = f2bf(hm0);                                               \
            hist[wslot][0][dim] = hb;                                         \
            ho[(size_t)tw * 128 + dim] = hb;                                  \
        }                                                                     \
        {   /* m = 1 */                                                       \
            float rr = sigm(bf2f((u16)((XR) >> 16)) + a0[1] + br);            \
            float zg = sigm(bf2f((u16)((XZ) >> 16)) + a1[1] + bz);            \
            float nn = tanh_fast(bf2f((u16)((XN) >> 16)) + rr * (a2[1] + bn));\
            hm1 = (1.f - zg) * nn + zg * hm1;                                 \
            u16 hb = f2bf(hm1);                                               \
            hist[wslot][1][dim] = hb;                                         \
            ho[16384 + (size_t)tw * 128 + dim] = hb;                          \
        }                                                                     \
        int t2 = (T) + 2; if (t2 > 127) t2 = 127;                             \
        XR = *(const unsigned*)(xpz + ((size_t)(t2 * 3 + 0) * 128 + dim) * 8);\
        XZ = *(const unsigned*)(xpz + ((size_t)(t2 * 3 + 1) * 128 + dim) * 8);\
        XN = *(const unsigned*)(xpz + ((size_t)(t2 * 3 + 2) * 128 + dim) * 8);\
    }                                                                         \
    STEP_BAR();                                                               \
}

__global__ __launch_bounds__(512)
void k3_gru(const u16* __restrict__ xp2,      // [2][128][3][128][8] bf16
            const float* __restrict__ whf, const float* __restrict__ bhf,
            const float* __restrict__ whb, const float* __restrict__ bhb,
            u16* __restrict__ hout)           // [2][8][128][128] bf16
{
    const int z   = blockIdx.x >> 2;
    const int bp  = blockIdx.x & 3;           // batches 2bp, 2bp+1
    const int tid = threadIdx.x;
    const int w   = tid >> 6;
    const int l   = tid & 63;
    const int nr  = l & 15;
    const int kb  = (l >> 4) * 8;
    const int dim = w * 16 + l;               // valid for l<16

    __shared__ __align__(16) u16 hist[2][2][128];   // [slot][m][hidden] 1 KB

    const float* W  = z ? whb : whf;
    const float* bh = z ? bhb : bhf;

    // W_hh B-frags (hi/lo bf16) in VGPRs: wave w owns n-tiles {w, w+8, w+16}
    bf16x8 Whi[3][4], Wlo[3][4];
    #pragma unroll
    for (int g = 0; g < 3; g++) {
        #pragma unroll
        for (int kt = 0; kt < 4; kt++) {
            const float* src = W + (size_t)(g * 128 + w * 16 + nr) * 128 + kt * 32 + kb;
            float4 w0 = *(const float4*)src;
            float4 w1 = *(const float4*)(src + 4);
            float v[8] = {w0.x, w0.y, w0.z, w0.w, w1.x, w1.y, w1.z, w1.w};
            bf16x8 hi, lo;
            #pragma unroll
            for (int jj = 0; jj < 8; jj++) {
                u16 hb = f2bf(v[jj]);
                hi[jj] = (short)hb;
                lo[jj] = (short)f2bf(v[jj] - bf2f(hb));
            }
            Whi[g][kt] = hi;
            Wlo[g][kt] = lo;
        }
    }

    float br = 0.f, bz = 0.f, bn = 0.f;
    float hm0 = 0.f, hm1 = 0.f;
    const u16* xpz = xp2 + (size_t)z * 393216 + 2 * bp;
    u16* ho = hout + (size_t)z * 131072 + (size_t)(2 * bp) * 16384;

    unsigned xAr = 0, xAz = 0, xAn = 0, xBr = 0, xBz = 0, xBn = 0;
    if (l < 16) {
        br = bh[dim]; bz = bh[dim + 128]; bn = bh[dim + 256];
        xAr = *(const unsigned*)(xpz + ((size_t)(0 * 3 + 0) * 128 + dim) * 8);
        xAz = *(const unsigned*)(xpz + ((size_t)(0 * 3 + 1) * 128 + dim) * 8);
        xAn = *(const unsigned*)(xpz + ((size_t)(0 * 3 + 2) * 128 + dim) * 8);
        xBr = *(const unsigned*)(xpz + ((size_t)(1 * 3 + 0) * 128 + dim) * 8);
        xBz = *(const unsigned*)(xpz + ((size_t)(1 * 3 + 1) * 128 + dim) * 8);
        xBn = *(const unsigned*)(xpz + ((size_t)(1 * 3 + 2) * 128 + dim) * 8);
    }
    if (tid < 256) ((unsigned*)hist)[tid] = 0u;    // h = 0 (both slots)
    __syncthreads();

    for (int c = 0; c < 64; c++) {
        K3_STEP(2 * c,     xAr, xAz, xAn)
        K3_STEP(2 * c + 1, xBr, xBz, xBn)
    }
}

// ---------------------------------------------------------------------------
// K4: MLP head. 1024 blocks = (b,t), 128 threads. (unchanged)
// ---------------------------------------------------------------------------
__global__ __launch_bounds__(128)
void k4_mlp(const u16* __restrict__ hout,
            const float* __restrict__ w1, const float* __restrict__ b1,
            const float* __restrict__ w2, const float* __restrict__ b2,
            float* __restrict__ out)
{
    const int bq  = blockIdx.x;
    const int tid = threadIdx.x;

    __shared__ __align__(16) float hrow[256];
    __shared__ float hid[50];

    const u16* hf = hout + (size_t)bq * 128;
    const u16* hb = hout + (size_t)8 * 128 * 128 + (size_t)bq * 128;
    hrow[tid]       = bf2f(hf[tid]);
    hrow[128 + tid] = bf2f(hb[tid]);
    __syncthreads();

    if (tid < 50) {
        float a = b1[tid];
        const float* wr = w1 + (size_t)tid * 256;
        for (int k0 = 0; k0 < 256; k0 += 8) {
            float4 wv0 = *(const float4*)&wr[k0];
            float4 wv1 = *(const float4*)&wr[k0 + 4];
            float4 h0  = *(const float4*)&hrow[k0];
            float4 h1  = *(const float4*)&hrow[k0 + 4];
            a += wv0.x * h0.x + wv0.y * h0.y + wv0.z * h0.z + wv0.w * h0.w;
            a += wv1.x * h1.x + wv1.y * h1.y + wv1.z * h1.z + wv1.w * h1.w;
        }
        hid[tid] = fmaxf(a, 0.f);
    }
    __syncthreads();
    if (tid < 64) {
        float a = b2[tid];
        const float* wr = w2 + (size_t)tid * 50;
        for (int k = 0; k < 50; k++) a += wr[k] * hid[k];
        out[(size_t)bq * 64 + tid] = a;
    }
}

// ---------------------------------------------------------------------------
// Workspace (2.0 MB): [0,512K) outb (K1->K2), reused as hout (K3->K4);
//                     [512K,2.0M) XP2 (K2->K3, gate-consumption layout).
// ---------------------------------------------------------------------------
extern "C" void kernel_launch(void* const* d_in, const int* in_sizes, int n_in,
                              void* d_out, int out_size, void* d_ws, size_t ws_size,
                              hipStream_t stream)
{
    const float* x    = (const float*)d_in[0];
    const float* ts   = (const float*)d_in[1];
    const float* qy   = (const float*)d_in[2];
    const float* bww  = (const float*)d_in[3];
    const float* cw   = (const float*)d_in[4];
    const float* cb   = (const float*)d_in[5];
    const float* wihf = (const float*)d_in[6];
    const float* whhf = (const float*)d_in[7];
    const float* bihf = (const float*)d_in[8];
    const float* bhhf = (const float*)d_in[9];
    const float* wihb = (const float*)d_in[10];
    const float* whhb = (const float*)d_in[11];
    const float* bihb = (const float*)d_in[12];
    const float* bhhb = (const float*)d_in[13];
    const float* w1   = (const float*)d_in[14];
    const float* b1   = (const float*)d_in[15];
    const float* w2   = (const float*)d_in[16];
    const float* b2   = (const float*)d_in[17];
    float* out = (float*)d_out;

    char* ws = (char*)d_ws;
    u16* outb = (u16*)ws;                     // 512 KB
    u16* hout = (u16*)ws;                     // alias (outb dead after K2)
    u16* xp2  = (u16*)(ws + 512 * 1024);      // 1.5 MB

    k1_attn_cross<<<256, 256, 0, stream>>>(x, ts, qy, bww, cw, cb, outb);
    k2_xp<<<768, 256, 0, stream>>>(outb, wihf, bihf, wihb, bihb, xp2);
    k3_gru<<<8, 512, 0, stream>>>(xp2, whhf, bhhf, whhb, bhhb, hout);
    k4_mlp<<<1024, 128, 0, stream>>>(hout, w1, b1, w2, b2, out);
}

// Round 9
// 162.818 us; speedup vs baseline: 1.7592x; 1.2110x over previous
//
#include <hip/hip_runtime.h>

typedef unsigned short u16;
typedef __attribute__((ext_vector_type(8))) short bf16x8;
typedef __attribute__((ext_vector_type(4))) float f32x4;

#define LOG2E 1.4426950408889634f

__device__ __forceinline__ float bf2f(u16 v) {
    union { unsigned u; float f; } x; x.u = ((unsigned)v) << 16; return x.f;
}
__device__ __forceinline__ u16 f2bf(float f) {
    union { float f; unsigned u; } x; x.f = f;
    unsigned u = x.u;
    u += 0x7FFFu + ((u >> 16) & 1u);   // round-to-nearest-even
    return (u16)(u >> 16);
}
__device__ __forceinline__ float sigm(float x) {
    return __builtin_amdgcn_rcpf(1.f + __builtin_amdgcn_exp2f(-x * LOG2E));
}
__device__ __forceinline__ float tanh_fast(float y) {
    float e = __builtin_amdgcn_exp2f(y * (2.f * LOG2E));
    return 1.f - 2.f * __builtin_amdgcn_rcpf(e + 1.f);   // saturates to +-1 safely
}
// raw barrier: LDS visibility only, NO vmem drain (keeps prefetch/stores in flight)
#define STEP_BAR() asm volatile("s_waitcnt lgkmcnt(0)\ns_barrier" ::: "memory")

// ---------------------------------------------------------------------------
// K1: time-kernel attention + cross projection. Inputs fp32. (unchanged)
// ---------------------------------------------------------------------------
__global__ __launch_bounds__(256)
void k1_attn_cross(const float* __restrict__ x, const float* __restrict__ ts,
                   const float* __restrict__ qy, const float* __restrict__ bww,
                   const float* __restrict__ cw, const float* __restrict__ cb,
                   u16* __restrict__ outb)
{
    const int blk = blockIdx.x;
    const int b  = blk >> 5;
    const int q0 = (blk & 31) * 4;
    const int d  = threadIdx.x;
    const int dm = 128 + (d & 127);

    __shared__ __align__(16) float sc[4][512];
    __shared__ __align__(16) float xs[2][2048];
    __shared__ __align__(16) float attn[4][256];

    for (int i = d; i < 4 * 512; i += 256) {
        int qq = i >> 9, s = i & 511;
        float diff = qy[q0 + qq] - ts[b * 512 + s];
        sc[qq][s] = -diff * diff;
    }
    float w  = bww[d];
    float kk = log1pf(expf(w)) * LOG2E;

    const float* xb = x + (size_t)b * 512 * 256;
    *(float4*)&xs[0][d * 8]     = *(const float4*)&xb[d * 8];
    *(float4*)&xs[0][d * 8 + 4] = *(const float4*)&xb[d * 8 + 4];
    __syncthreads();

    float num[4] = {0.f, 0.f, 0.f, 0.f}, den[4] = {0.f, 0.f, 0.f, 0.f};
    for (int s0 = 0; s0 < 512; s0 += 8) {
        int cur = (s0 >> 3) & 1;
        if (s0 + 8 < 512) {
            const float* src = &xb[(s0 + 8) * 256 + d * 8];
            *(float4*)&xs[cur ^ 1][d * 8]     = *(const float4*)&src[0];
            *(float4*)&xs[cur ^ 1][d * 8 + 4] = *(const float4*)&src[4];
        }
        #pragma unroll
        for (int ss = 0; ss < 8; ss++) {
            float xv  = xs[cur][ss * 256 + d];
            float mv  = xs[cur][ss * 256 + dm];
            float mxv = mv * xv;
            #pragma unroll
            for (int qq = 0; qq < 4; qq++) {
                float p = exp2f(sc[qq][s0 + ss] * kk);
                num[qq] += p * mxv;
                den[qq] += p * mv;
            }
        }
        __syncthreads();
    }
    #pragma unroll
    for (int qq = 0; qq < 4; qq++)
        attn[qq][d] = num[qq] / fmaxf(den[qq], 1e-30f);
    __syncthreads();

    float cbv = cb[d];
    float acc[4] = {cbv, cbv, cbv, cbv};
    const float* wr = cw + (size_t)d * 256;
    for (int k0 = 0; k0 < 256; k0 += 4) {
        float4 wv = *(const float4*)&wr[k0];
        float4 a0 = *(const float4*)&attn[0][k0];
        float4 a1 = *(const float4*)&attn[1][k0];
        float4 a2 = *(const float4*)&attn[2][k0];
        float4 a3 = *(const float4*)&attn[3][k0];
        acc[0] += wv.x * a0.x + wv.y * a0.y + wv.z * a0.z + wv.w * a0.w;
        acc[1] += wv.x * a1.x + wv.y * a1.y + wv.z * a1.z + wv.w * a1.w;
        acc[2] += wv.x * a2.x + wv.y * a2.y + wv.z * a2.z + wv.w * a2.w;
        acc[3] += wv.x * a3.x + wv.y * a3.y + wv.z * a3.z + wv.w * a3.w;
    }
    #pragma unroll
    for (int qq = 0; qq < 4; qq++)
        outb[(size_t)(b * 128 + q0 + qq) * 256 + d] = f2bf(acc[qq]);
}

// ---------------------------------------------------------------------------
// K2: xp via MFMA, gate-consumption layout XP2[z][tau][g][dim][b] bf16,
// tau = (z ? 127-t : t). (unchanged)
// ---------------------------------------------------------------------------
__global__ __launch_bounds__(256)
void k2_xp(const u16* __restrict__ outb,
           const float* __restrict__ wf, const float* __restrict__ bf_,
           const float* __restrict__ wb, const float* __restrict__ bb_,
           u16* __restrict__ xp2)    // [2][128][3][128][8] bf16
{
    const int wid  = threadIdx.x >> 6;
    const int lane = threadIdx.x & 63;
    int gw = blockIdx.x * 4 + wid;
    int z  = (gw >= 1536) ? 1 : 0;
    int t  = gw - z * 1536;
    int rt = t / 24, nt = t - rt * 24;
    int r0 = rt * 16, n0 = nt * 16;

    const float* W  = z ? wb  : wf;
    const float* Bv = z ? bb_ : bf_;

    const u16*   arow = outb + (size_t)(r0 + (lane & 15)) * 256 + (lane >> 4) * 8;
    const float* brow = W    + (size_t)(n0 + (lane & 15)) * 256 + (lane >> 4) * 8;

    f32x4 acc = {0.f, 0.f, 0.f, 0.f};
    #pragma unroll
    for (int k = 0; k < 8; k++) {
        bf16x8 a = *(const bf16x8*)(arow + k * 32);
        float4 w0 = *(const float4*)(brow + k * 32);
        float4 w1 = *(const float4*)(brow + k * 32 + 4);
        bf16x8 bfrag;
        bfrag[0] = (short)f2bf(w0.x); bfrag[1] = (short)f2bf(w0.y);
        bfrag[2] = (short)f2bf(w0.z); bfrag[3] = (short)f2bf(w0.w);
        bfrag[4] = (short)f2bf(w1.x); bfrag[5] = (short)f2bf(w1.y);
        bfrag[6] = (short)f2bf(w1.z); bfrag[7] = (short)f2bf(w1.w);
        acc = __builtin_amdgcn_mfma_f32_16x16x32_bf16(a, bfrag, acc, 0, 0, 0);
    }
    int col   = n0 + (lane & 15);
    int rbase = r0 + (lane >> 4) * 4;
    float bias = Bv[col];
    int g  = col >> 7;
    int dv = col & 127;
    u16* xpz = xp2 + (size_t)z * 393216;
    #pragma unroll
    for (int i = 0; i < 4; i++) {
        int r  = rbase + i;
        int bb = r >> 7;
        int tt = r & 127;
        int tau = z ? (127 - tt) : tt;
        xpz[((size_t)(tau * 3 + g) * 128 + dv) * 8 + bb] = f2bf(acc[i] + bias);
    }
}

// ---------------------------------------------------------------------------
// K3: bidirectional GRU, 8 blocks = (dir z, batch-pair bp), 512 thr (8 waves).
// Round-9 changes vs round-8:
//  * W_hh single bf16 (Wlo MFMAs dropped): 12 MFMA/wave/step instead of 24.
//    (absmax was staging-dominated & constant across fp32/bf16 W -- gamble.)
//  * batch 0 -> A row 0, batch 1 -> A row 4: C rows 0 and 4 land in acc[0]
//    of lanes 0-15 and 16-31 resp., so lanes 0-31 each run ONE gate chain
//    (halves serial gate latency, doubles active lanes).
// h: fp32 master in regs (1/lane); bf16 copy in 2-slot LDS ring. xp straight
// from global, 2-step register prefetch (per-lane u16). ONE raw barrier/step.
// hout written at tw = z ? 127-T : T (xp2 is tau-indexed, hout t-indexed).
// ---------------------------------------------------------------------------
#define K3_STEP(T, XR, XZ, XN) {                                              \
    const int rslot = ((T) + 1) & 1, wslot = (T) & 1;                         \
    bf16x8 A0 = {0,0,0,0,0,0,0,0}, A1 = {0,0,0,0,0,0,0,0};                    \
    bf16x8 A2 = {0,0,0,0,0,0,0,0}, A3 = {0,0,0,0,0,0,0,0};                    \
    if ((nr & 3) == 0 && nr < 8) {   /* rows 0,4 hold batches 0,1 */          \
        const u16* hb_ = &hist[rslot][nr >> 2][0];                            \
        A0 = *(const bf16x8*)&hb_[kb];                                        \
        A1 = *(const bf16x8*)&hb_[32 + kb];                                   \
        A2 = *(const bf16x8*)&hb_[64 + kb];                                   \
        A3 = *(const bf16x8*)&hb_[96 + kb];                                   \
    }                                                                         \
    f32x4 a0 = {0.f,0.f,0.f,0.f}, a1 = a0, a2 = a0;                           \
    a0 = __builtin_amdgcn_mfma_f32_16x16x32_bf16(A0, Whi[0][0], a0, 0,0,0);   \
    a1 = __builtin_amdgcn_mfma_f32_16x16x32_bf16(A0, Whi[1][0], a1, 0,0,0);   \
    a2 = __builtin_amdgcn_mfma_f32_16x16x32_bf16(A0, Whi[2][0], a2, 0,0,0);   \
    a0 = __builtin_amdgcn_mfma_f32_16x16x32_bf16(A1, Whi[0][1], a0, 0,0,0);   \
    a1 = __builtin_amdgcn_mfma_f32_16x16x32_bf16(A1, Whi[1][1], a1, 0,0,0);   \
    a2 = __builtin_amdgcn_mfma_f32_16x16x32_bf16(A1, Whi[2][1], a2, 0,0,0);   \
    a0 = __builtin_amdgcn_mfma_f32_16x16x32_bf16(A2, Whi[0][2], a0, 0,0,0);   \
    a1 = __builtin_amdgcn_mfma_f32_16x16x32_bf16(A2, Whi[1][2], a1, 0,0,0);   \
    a2 = __builtin_amdgcn_mfma_f32_16x16x32_bf16(A2, Whi[2][2], a2, 0,0,0);   \
    a0 = __builtin_amdgcn_mfma_f32_16x16x32_bf16(A3, Whi[0][3], a0, 0,0,0);   \
    a1 = __builtin_amdgcn_mfma_f32_16x16x32_bf16(A3, Whi[1][3], a1, 0,0,0);   \
    a2 = __builtin_amdgcn_mfma_f32_16x16x32_bf16(A3, Whi[2][3], a2, 0,0,0);   \
    if (l < 32) {                                                             \
        const int tw = z ? (127 - (T)) : (T);                                 \
        float rr = sigm(bf2f(XR) + a0[0] + br);                               \
        float zg = sigm(bf2f(XZ) + a1[0] + bz);                               \
        float nn = tanh_fast(bf2f(XN) + rr * (a2[0] + bn));                   \
        hm = (1.f - zg) * nn + zg * hm;                                       \
        u16 hb = f2bf(hm);                                                    \
        hist[wslot][gm][gdim] = hb;                                           \
        ho[(size_t)gm * 16384 + (size_t)tw * 128 + gdim] = hb;                \
        int t2 = (T) + 2; if (t2 > 127) t2 = 127;                             \
        XR = xpz[((size_t)(t2 * 3 + 0) * 128 + gdim) * 8 + gm];               \
        XZ = xpz[((size_t)(t2 * 3 + 1) * 128 + gdim) * 8 + gm];               \
        XN = xpz[((size_t)(t2 * 3 + 2) * 128 + gdim) * 8 + gm];               \
    }                                                                         \
    STEP_BAR();                                                               \
}

__global__ __launch_bounds__(512)
void k3_gru(const u16* __restrict__ xp2,      // [2][128][3][128][8] bf16
            const float* __restrict__ whf, const float* __restrict__ bhf,
            const float* __restrict__ whb, const float* __restrict__ bhb,
            u16* __restrict__ hout)           // [2][8][128][128] bf16
{
    const int z   = blockIdx.x >> 2;
    const int bp  = blockIdx.x & 3;           // batches 2bp, 2bp+1
    const int tid = threadIdx.x;
    const int w   = tid >> 6;
    const int l   = tid & 63;
    const int nr  = l & 15;
    const int kb  = (l >> 4) * 8;
    const int gm   = l >> 4;                  // gate batch (valid l<32)
    const int gdim = w * 16 + (l & 15);       // gate hidden dim (valid l<32)

    __shared__ __align__(16) u16 hist[2][2][128];   // [slot][m][hidden] 1 KB

    const float* W  = z ? whb : whf;
    const float* bh = z ? bhb : bhf;

    // W_hh B-frags (bf16) in VGPRs: wave w owns n-tiles {w, w+8, w+16}
    bf16x8 Whi[3][4];
    #pragma unroll
    for (int g = 0; g < 3; g++) {
        #pragma unroll
        for (int kt = 0; kt < 4; kt++) {
            const float* src = W + (size_t)(g * 128 + w * 16 + nr) * 128 + kt * 32 + kb;
            float4 w0 = *(const float4*)src;
            float4 w1 = *(const float4*)(src + 4);
            bf16x8 hi;
            hi[0] = (short)f2bf(w0.x); hi[1] = (short)f2bf(w0.y);
            hi[2] = (short)f2bf(w0.z); hi[3] = (short)f2bf(w0.w);
            hi[4] = (short)f2bf(w1.x); hi[5] = (short)f2bf(w1.y);
            hi[6] = (short)f2bf(w1.z); hi[7] = (short)f2bf(w1.w);
            Whi[g][kt] = hi;
        }
    }

    float br = 0.f, bz = 0.f, bn = 0.f;
    float hm = 0.f;
    const u16* xpz = xp2 + (size_t)z * 393216 + 2 * bp;   // +gm per lane
    u16* ho = hout + (size_t)z * 131072 + (size_t)(2 * bp) * 16384;

    u16 xAr = 0, xAz = 0, xAn = 0, xBr = 0, xBz = 0, xBn = 0;
    if (l < 32) {
        br = bh[gdim]; bz = bh[gdim + 128]; bn = bh[gdim + 256];
        xAr = xpz[((size_t)(0 * 3 + 0) * 128 + gdim) * 8 + gm];
        xAz = xpz[((size_t)(0 * 3 + 1) * 128 + gdim) * 8 + gm];
        xAn = xpz[((size_t)(0 * 3 + 2) * 128 + gdim) * 8 + gm];
        xBr = xpz[((size_t)(1 * 3 + 0) * 128 + gdim) * 8 + gm];
        xBz = xpz[((size_t)(1 * 3 + 1) * 128 + gdim) * 8 + gm];
        xBn = xpz[((size_t)(1 * 3 + 2) * 128 + gdim) * 8 + gm];
    }
    if (tid < 256) ((unsigned*)hist)[tid] = 0u;    // h = 0 (both slots)
    __syncthreads();

    for (int c = 0; c < 64; c++) {
        K3_STEP(2 * c,     xAr, xAz, xAn)
        K3_STEP(2 * c + 1, xBr, xBz, xBn)
    }
}

// ---------------------------------------------------------------------------
// K4: MLP head. 1024 blocks = (b,t), 128 threads. (unchanged)
// ---------------------------------------------------------------------------
__global__ __launch_bounds__(128)
void k4_mlp(const u16* __restrict__ hout,
            const float* __restrict__ w1, const float* __restrict__ b1,
            const float* __restrict__ w2, const float* __restrict__ b2,
            float* __restrict__ out)
{
    const int bq  = blockIdx.x;
    const int tid = threadIdx.x;

    __shared__ __align__(16) float hrow[256];
    __shared__ float hid[50];

    const u16* hf = hout + (size_t)bq * 128;
    const u16* hb = hout + (size_t)8 * 128 * 128 + (size_t)bq * 128;
    hrow[tid]       = bf2f(hf[tid]);
    hrow[128 + tid] = bf2f(hb[tid]);
    __syncthreads();

    if (tid < 50) {
        float a = b1[tid];
        const float* wr = w1 + (size_t)tid * 256;
        for (int k0 = 0; k0 < 256; k0 += 8) {
            float4 wv0 = *(const float4*)&wr[k0];
            float4 wv1 = *(const float4*)&wr[k0 + 4];
            float4 h0  = *(const float4*)&hrow[k0];
            float4 h1  = *(const float4*)&hrow[k0 + 4];
            a += wv0.x * h0.x + wv0.y * h0.y + wv0.z * h0.z + wv0.w * h0.w;
            a += wv1.x * h1.x + wv1.y * h1.y + wv1.z * h1.z + wv1.w * h1.w;
        }
        hid[tid] = fmaxf(a, 0.f);
    }
    __syncthreads();
    if (tid < 64) {
        float a = b2[tid];
        const float* wr = w2 + (size_t)tid * 50;
        for (int k = 0; k < 50; k++) a += wr[k] * hid[k];
        out[(size_t)bq * 64 + tid] = a;
    }
}

// ---------------------------------------------------------------------------
// Workspace (2.0 MB): [0,512K) outb (K1->K2), reused as hout (K3->K4);
//                     [512K,2.0M) XP2 (K2->K3, gate-consumption layout).
// ---------------------------------------------------------------------------
extern "C" void kernel_launch(void* const* d_in, const int* in_sizes, int n_in,
                              void* d_out, int out_size, void* d_ws, size_t ws_size,
                              hipStream_t stream)
{
    const float* x    = (const float*)d_in[0];
    const float* ts   = (const float*)d_in[1];
    const float* qy   = (const float*)d_in[2];
    const float* bww  = (const float*)d_in[3];
    const float* cw   = (const float*)d_in[4];
    const float* cb   = (const float*)d_in[5];
    const float* wihf = (const float*)d_in[6];
    const float* whhf = (const float*)d_in[7];
    const float* bihf = (const float*)d_in[8];
    const float* bhhf = (const float*)d_in[9];
    const float* wihb = (const float*)d_in[10];
    const float* whhb = (const float*)d_in[11];
    const float* bihb = (const float*)d_in[12];
    const float* bhhb = (const float*)d_in[13];
    const float* w1   = (const float*)d_in[14];
    const float* b1   = (const float*)d_in[15];
    const float* w2   = (const float*)d_in[16];
    const float* b2   = (const float*)d_in[17];
    float* out = (float*)d_out;

    char* ws = (char*)d_ws;
    u16* outb = (u16*)ws;                     // 512 KB
    u16* hout = (u16*)ws;                     // alias (outb dead after K2)
    u16* xp2  = (u16*)(ws + 512 * 1024);      // 1.5 MB

    k1_attn_cross<<<256, 256, 0, stream>>>(x, ts, qy, bww, cw, cb, outb);
    k2_xp<<<768, 256, 0, stream>>>(outb, wihf, bihf, wihb, bihb, xp2);
    k3_gru<<<8, 512, 0, stream>>>(xp2, whhf, bhhf, whhb, bhhb, hout);
    k4_mlp<<<1024, 128, 0, stream>>>(hout, w1, b1, w2, b2, out);
}